// Round 2
// baseline (112.039 us; speedup 1.0000x reference)
//
#include <hip/hip_runtime.h>
#include <float.h>
#include <math.h>

// AdvancedLossFunction: total = 1.0*occ + 0.1*smooth + 0.01*sparse + 0.1*cons
// R15: MFMA knn with 16-j candidate groups (was 4-j quartets).
//   t(i,j) = -2 p_i.q_j + |q_j|^2 via v_mfma_f32_32x32x16_bf16, 2-way bf16
//   hi/lo split packing (K=14 of 16), same as R14 (absmax 0).
// C/D layout: col=lane&31 (i), row=(reg&3)+8*(reg>>2)+4*(lane>>5) (j):
//   regs 0-7 cover rows [0,16), regs 8-15 rows [16,32) FOR BOTH lane halves
//   -> per tile only 2 group keys/lane (8-way min tree each), ~20 VALU/tile
//   vs R14's 38 (4 quartet keys). Group id = j/16 in [0,1024) = 10 bits ->
//   key keeps 22 value bits (4x finer than R14's 20 -> tie risk lower).
// Halves now share ids (id has no h bit): cross-half shfl merge does a
//   one-time 16-pair id-dedup (drop larger of dup pair, re-sort 8 -> top-4
//   DISTINCT ids). Coverage: {self,NN1..3} in <=4 groups; keys <= t(NN3)
//   are in their half's top-4; distinct-id top-4 of merged 8 covers them.
// merge decodes 4 groups x 16 = 64 candidates, exact d2 + index self-excl.
// Fill ~40us is harness ws poison (uncontrollable).

constexpr int   N_ = 16384;
constexpr int   F_ = 64;
constexpr float OCC_W = 1.0f, SMOOTH_W = 0.1f, SPARSE_W = 0.01f, CONS_W = 0.1f;
constexpr float EPS_ = 1e-7f;

constexpr int CHUNKS  = 16;
constexpr int CHUNK_J = N_ / CHUNKS;    // 1024 j's per chunk
constexpr int JTILES  = CHUNK_J / 32;   // 32 MFMA j-tiles per chunk
constexpr int IB      = 128;            // i's per block (4 waves x 32)
constexpr int IBLOCKS = N_ / IB;        // 128

typedef __attribute__((ext_vector_type(8)))  short bf16x8;
typedef __attribute__((ext_vector_type(16))) float f32x16;

union U128 { uint4 u; bf16x8 s; };

__device__ __forceinline__ void ins4f(float t, float& b0, float& b1, float& b2, float& b3) {
  // maintains b0<=b1<=b2<=b3
  float n0 = fminf(b0, t);
  float n1 = __builtin_amdgcn_fmed3f(b0, b1, t);
  float n2 = __builtin_amdgcn_fmed3f(b1, b2, t);
  float n3 = __builtin_amdgcn_fmed3f(b2, b3, t);
  b0 = n0; b1 = n1; b2 = n2; b3 = n3;
}

// RNE split x = hi + lo (both bf16); returns 16-bit payloads.
__device__ __forceinline__ void split2(float x, unsigned& h16, unsigned& l16) {
  unsigned u = __float_as_uint(x);
  unsigned r = u + 0x7FFFu + ((u >> 16) & 1u);
  h16 = r >> 16;
  float lo = x - __uint_as_float(r & 0xFFFF0000u);
  unsigned v = __float_as_uint(lo);
  l16 = (v + 0x7FFFu + ((v >> 16) & 1u)) >> 16;
}

// ws layout: 0: float4 part[256] | 4096: unsigned done | 8192: float4 cand[CHUNKS][N]

__global__ __launch_bounds__(256) void knn_mfma(const float* __restrict__ pts,
                                                float4* __restrict__ cand,
                                                unsigned* __restrict__ done) {
  if (blockIdx.x == 0 && threadIdx.x == 0) *done = 0u;
  __shared__ uint4 AF[2][CHUNK_J];      // packed A-frag halves, 32 KB
  const int tid   = threadIdx.x;
  const int chunk = blockIdx.x & (CHUNKS - 1);
  const int ibk   = blockIdx.x >> 4;    // log2(CHUNKS)
  const int j0    = chunk * CHUNK_J;

  // Stage j-side fragments: per j, Kvec as 8 packed words (2 bf16 each).
  for (int t = tid; t < CHUNK_J; t += 256) {
    int j = j0 + t;
    float qx = pts[3 * j], qy = pts[3 * j + 1], qz = pts[3 * j + 2];
    float w  = fmaf(qx, qx, fmaf(qy, qy, qz * qz));
    unsigned Hx, Lx, Hy, Ly, Hz, Lz, Hw, Lw;
    split2(-2.f * qx, Hx, Lx);
    split2(-2.f * qy, Hy, Ly);
    split2(-2.f * qz, Hz, Lz);
    split2(w, Hw, Lw);
    AF[0][t] = make_uint4(Hx | (Hx << 16), Lx | (Lx << 16),
                          Hy | (Hy << 16), Ly | (Ly << 16));
    AF[1][t] = make_uint4(Hz | (Hz << 16), Lz | (Lz << 16),
                          Hw | (Lw << 16), 0u);
  }

  // i-side (B operand) fragment: resident for the whole kernel.
  const int lane = tid & 63, wv = tid >> 6;
  const int h = lane >> 5, il = lane & 31;
  const int i = ibk * IB + wv * 32 + il;
  U128 bf;
  {
    float x = pts[3 * i], y = pts[3 * i + 1], z = pts[3 * i + 2];
    unsigned hx, lx, hy, ly, hz, lz;
    split2(x, hx, lx);
    split2(y, hy, ly);
    split2(z, hz, lz);
    if (h == 0) {
      unsigned a = hx | (lx << 16), b = hy | (ly << 16);
      bf.u = make_uint4(a, a, b, b);
    } else {
      unsigned a = hz | (lz << 16);
      bf.u = make_uint4(a, a, 0x3F803F80u, 0u);   // bf16(1.0) pair
    }
  }
  __syncthreads();

  float b0 = FLT_MAX, b1 = FLT_MAX, b2 = FLT_MAX, b3 = FLT_MAX;
  const f32x16 zacc = {};                          // loop-invariant zero C operand
  const unsigned idb = (unsigned)(chunk * (CHUNK_J / 16));  // global 16-group id base
  const uint4* __restrict__ afp = &AF[h][0];

#pragma unroll 4
  for (int t = 0; t < JTILES; ++t) {
    U128 af; af.u = afp[t * 32 + il];              // conflict-free b128
    f32x16 acc = __builtin_amdgcn_mfma_f32_32x32x16_bf16(af.s, bf.s, zacc, 0, 0, 0);
    // group 2t: rows [0,16) of tile = regs 0..7 (both halves)
    float m0 = fminf(fminf(fminf(acc[0], acc[1]), fminf(acc[2], acc[3])),
                     fminf(fminf(acc[4], acc[5]), fminf(acc[6], acc[7])));
    float k0 = __uint_as_float((__float_as_uint(m0) & 0xFFFFFC00u) | (idb + 2u * t));
    ins4f(k0, b0, b1, b2, b3);
    // group 2t+1: rows [16,32) = regs 8..15
    float m1 = fminf(fminf(fminf(acc[8], acc[9]), fminf(acc[10], acc[11])),
                     fminf(fminf(acc[12], acc[13]), fminf(acc[14], acc[15])));
    float k1 = __uint_as_float((__float_as_uint(m1) & 0xFFFFFC00u) | (idb + 2u * t + 1u));
    ins4f(k1, b0, b1, b2, b3);
  }

  // Cross-half merge. Halves hold partial minima over disjoint ROW subsets of
  // the SAME group ids -> dedup: for each duplicate id pair keep the smaller,
  // mark the larger +inf, then re-sort the 8 survivors to a top-4.
  float o0 = __shfl_xor(b0, 32), o1 = __shfl_xor(b1, 32),
        o2 = __shfl_xor(b2, 32), o3 = __shfl_xor(b3, 32);
  {
    float B[4] = {b0, b1, b2, b3};
    float O[4] = {o0, o1, o2, o3};
    unsigned ibd[4], iod[4];
#pragma unroll
    for (int k = 0; k < 4; ++k) {
      ibd[k] = __float_as_uint(B[k]) & 0x3FFu;
      iod[k] = __float_as_uint(O[k]) & 0x3FFu;
    }
#pragma unroll
    for (int k = 0; k < 4; ++k) {
#pragma unroll
      for (int m = 0; m < 4; ++m) {
        bool dup = (iod[k] == ibd[m]);
        bool om  = dup && (O[k] >= B[m]);
        bool bm  = dup && (O[k] <  B[m]);
        if (om) O[k] = FLT_MAX;
        if (bm) B[m] = FLT_MAX;
      }
    }
    b0 = b1 = b2 = b3 = FLT_MAX;
#pragma unroll
    for (int k = 0; k < 4; ++k) ins4f(B[k], b0, b1, b2, b3);
#pragma unroll
    for (int k = 0; k < 4; ++k) ins4f(O[k], b0, b1, b2, b3);
  }
  if (h == 0) cand[(size_t)chunk * N_ + i] = make_float4(b0, b1, b2, b3);
}

// grid 256: 64 i's per block; 4 waves scan 4 chunks each; wave 0 merges, decodes
// 4 groups -> 64 candidates, exact d2 + index self-exclusion -> smoothness.
__global__ __launch_bounds__(256) void merge_kernel(const float* __restrict__ pred,
                                                    const float* __restrict__ targ,
                                                    const float* __restrict__ feat,
                                                    const float* __restrict__ pts,
                                                    const float4* __restrict__ cand,
                                                    float4* __restrict__ part,
                                                    unsigned* __restrict__ done,
                                                    float* __restrict__ out) {
  __shared__ float4 sh[256];
  __shared__ float ws4[4][4];
  __shared__ int is_last;
  constexpr int CPT = CHUNKS / 4;                  // 4 chunks per sub-wave
  int tid  = threadIdx.x;
  int lane = tid & 63;
  int sub  = tid >> 6;
  int i = blockIdx.x * 64 + lane;

  const float4* f4 = (const float4*)feat;
  float s_sp = 0.f;
#pragma unroll
  for (int s = 0; s < 4; ++s) {
    float4 v = f4[(size_t)s * 65536 + blockIdx.x * 256 + tid];
    s_sp += fabsf(v.x) + fabsf(v.y) + fabsf(v.z) + fabsf(v.w);
  }

  float b0 = FLT_MAX, b1 = FLT_MAX, b2 = FLT_MAX, b3 = FLT_MAX;
#pragma unroll
  for (int cc = 0; cc < CPT; ++cc) {
    float4 v = cand[(size_t)(sub * CPT + cc) * N_ + i];
    ins4f(v.x, b0, b1, b2, b3);
    ins4f(v.y, b0, b1, b2, b3);
    ins4f(v.z, b0, b1, b2, b3);
    ins4f(v.w, b0, b1, b2, b3);
  }
  sh[tid] = make_float4(b0, b1, b2, b3);
  __syncthreads();

  float s_occ = 0.f, s_cons = 0.f, s_sm = 0.f;
  if (sub == 0) {
#pragma unroll
    for (int w = 1; w < 4; ++w) {
      float4 v = sh[w * 64 + lane];
      ins4f(v.x, b0, b1, b2, b3);
      ins4f(v.y, b0, b1, b2, b3);
      ins4f(v.z, b0, b1, b2, b3);
      ins4f(v.w, b0, b1, b2, b3);
    }
    unsigned qarr[4] = {__float_as_uint(b0) & 0x3FFu, __float_as_uint(b1) & 0x3FFu,
                        __float_as_uint(b2) & 0x3FFu, __float_as_uint(b3) & 0x3FFu};
    float xi = pts[3 * i], yi = pts[3 * i + 1], zi = pts[3 * i + 2];
    float c0 = FLT_MAX, c1 = FLT_MAX, c2 = FLT_MAX;
    float p0 = 0.f, p1 = 0.f, p2 = 0.f;
#pragma unroll
    for (int s = 0; s < 4; ++s) {
#pragma unroll 8
      for (int m = 0; m < 16; ++m) {
        int j = (int)(qarr[s] * 16 + m);           // 16-group decode
        float dx = xi - pts[3 * j], dy = yi - pts[3 * j + 1], dz = zi - pts[3 * j + 2];
        float d2 = fmaf(dx, dx, fmaf(dy, dy, dz * dz));
        float pj = pred[j];
        if (j != i && d2 < c2) {                   // exact top-3, self excluded
          bool cc0 = d2 < c0, cc1 = d2 < c1;
          float n2 = cc1 ? c1 : d2;               float m2 = cc1 ? p1 : pj;
          float n1 = cc0 ? c0 : (cc1 ? d2 : c1);  float m1 = cc0 ? p0 : (cc1 ? pj : p1);
          float n0 = cc0 ? d2 : c0;               float m0 = cc0 ? pj : p0;
          c0 = n0; c1 = n1; c2 = n2; p0 = m0; p1 = m1; p2 = m2;
        }
      }
    }
    float pi = pred[i], tg = targ[i];
    float p  = fminf(fmaxf(pi, EPS_), 1.0f - EPS_);
    s_occ  = -(tg * __logf(p) + (1.0f - tg) * __logf(1.0f - p));
    float dd = pi - tg;
    s_cons = dd * dd;
    s_sm   = fabsf(pi - p0) + fabsf(pi - p1) + fabsf(pi - p2);
  }

  for (int off = 32; off > 0; off >>= 1) {
    s_sp   += __shfl_down(s_sp, off);
    s_occ  += __shfl_down(s_occ, off);
    s_cons += __shfl_down(s_cons, off);
    s_sm   += __shfl_down(s_sm, off);
  }
  if ((tid & 63) == 0) {
    int w = tid >> 6;
    ws4[w][0] = s_occ; ws4[w][1] = s_cons; ws4[w][2] = s_sp; ws4[w][3] = s_sm;
  }
  __syncthreads();
  if (tid == 0) {
    part[blockIdx.x] = make_float4(ws4[0][0] + ws4[1][0] + ws4[2][0] + ws4[3][0],
                                   ws4[0][1] + ws4[1][1] + ws4[2][1] + ws4[3][1],
                                   ws4[0][2] + ws4[1][2] + ws4[2][2] + ws4[3][2],
                                   ws4[0][3] + ws4[1][3] + ws4[2][3] + ws4[3][3]);
    __threadfence();
    unsigned prev = atomicAdd(done, 1u);
    is_last = (prev == (unsigned)(gridDim.x - 1));
  }
  __syncthreads();

  if (is_last) {
    __threadfence();
    float4 a = part[tid];
    float o = a.x, cn = a.y, sp = a.z, sm = a.w;
    for (int off = 32; off > 0; off >>= 1) {
      o  += __shfl_down(o, off);
      cn += __shfl_down(cn, off);
      sp += __shfl_down(sp, off);
      sm += __shfl_down(sm, off);
    }
    if ((tid & 63) == 0) {
      int w = tid >> 6;
      ws4[w][0] = o; ws4[w][1] = cn; ws4[w][2] = sp; ws4[w][3] = sm;
    }
    __syncthreads();
    if (tid == 0) {
      float occ  = ws4[0][0] + ws4[1][0] + ws4[2][0] + ws4[3][0];
      float cons = ws4[0][1] + ws4[1][1] + ws4[2][1] + ws4[3][1];
      float spar = ws4[0][2] + ws4[1][2] + ws4[2][2] + ws4[3][2];
      float smoo = ws4[0][3] + ws4[1][3] + ws4[2][3] + ws4[3][3];
      out[0] = OCC_W * (occ / (float)N_)
             + CONS_W * (cons / (float)N_)
             + SPARSE_W * (spar / (float)(N_ * F_))
             + SMOOTH_W * (smoo / (float)(N_ * 3));
    }
  }
}

extern "C" void kernel_launch(void* const* d_in, const int* in_sizes, int n_in,
                              void* d_out, int out_size, void* d_ws, size_t ws_size,
                              hipStream_t stream) {
  const float* pred = (const float*)d_in[0];
  const float* targ = (const float*)d_in[1];
  const float* feat = (const float*)d_in[2];
  const float* pts  = (const float*)d_in[3];
  float* out = (float*)d_out;

  char*     ws   = (char*)d_ws;
  float4*   part = (float4*)ws;
  unsigned* done = (unsigned*)(ws + 4096);
  float4*   cand = (float4*)(ws + 8192);

  knn_mfma<<<IBLOCKS * CHUNKS, 256, 0, stream>>>(pts, cand, done);
  merge_kernel<<<256, 256, 0, stream>>>(pred, targ, feat, pts, cand, part, done, out);
}

// Round 3
// 100.546 us; speedup vs baseline: 1.1143x; 1.1143x over previous
//
#include <hip/hip_runtime.h>
#include <float.h>
#include <math.h>

// AdvancedLossFunction: total = 1.0*occ + 0.1*smooth + 0.01*sparse + 0.1*cons
// R16: wave-parallel merge candidate phase (R15's 64-candidate decode ran on
//   ONE wave while 3 idled -> the regression term). Now: all 4 waves rebuild
//   the merged top-4 group list (cheap, uniform), wave `sub` evaluates group
//   qarr[sub] (16 exact-d2 candidates), per-wave top-3 (d2,pred) -> LDS ->
//   wave 0 merges 12 pairs -> exact top-3. 4x parallel on the serial tail.
// knn unchanged structurally (R15 16-j groups, v_mfma_f32_32x32x16_bf16,
//   2-way bf16 hi/lo split, absmax 0); micro: left-deep fmin chains (v_min3
//   fusion: 8-way min 7->4 insts), key pack shaped for v_and_or_b32, both
//   group keys computed before the dependent ins4f pair. ~18 VALU/tile.
// Cross-round clock noise is +/-10% (fills 45/40/41 us for identical 268MB);
//   fills are the internal clock reference. Fill is harness ws poison.

constexpr int   N_ = 16384;
constexpr int   F_ = 64;
constexpr float OCC_W = 1.0f, SMOOTH_W = 0.1f, SPARSE_W = 0.01f, CONS_W = 0.1f;
constexpr float EPS_ = 1e-7f;

constexpr int CHUNKS  = 16;
constexpr int CHUNK_J = N_ / CHUNKS;    // 1024 j's per chunk
constexpr int JTILES  = CHUNK_J / 32;   // 32 MFMA j-tiles per chunk
constexpr int IB      = 128;            // i's per block (4 waves x 32)
constexpr int IBLOCKS = N_ / IB;        // 128

typedef __attribute__((ext_vector_type(8)))  short bf16x8;
typedef __attribute__((ext_vector_type(16))) float f32x16;

union U128 { uint4 u; bf16x8 s; };

__device__ __forceinline__ void ins4f(float t, float& b0, float& b1, float& b2, float& b3) {
  // maintains b0<=b1<=b2<=b3
  float n0 = fminf(b0, t);
  float n1 = __builtin_amdgcn_fmed3f(b0, b1, t);
  float n2 = __builtin_amdgcn_fmed3f(b1, b2, t);
  float n3 = __builtin_amdgcn_fmed3f(b2, b3, t);
  b0 = n0; b1 = n1; b2 = n2; b3 = n3;
}

// RNE split x = hi + lo (both bf16); returns 16-bit payloads.
__device__ __forceinline__ void split2(float x, unsigned& h16, unsigned& l16) {
  unsigned u = __float_as_uint(x);
  unsigned r = u + 0x7FFFu + ((u >> 16) & 1u);
  h16 = r >> 16;
  float lo = x - __uint_as_float(r & 0xFFFF0000u);
  unsigned v = __float_as_uint(lo);
  l16 = (v + 0x7FFFu + ((v >> 16) & 1u)) >> 16;
}

// ws layout: 0: float4 part[256] | 4096: unsigned done | 8192: float4 cand[CHUNKS][N]

__global__ __launch_bounds__(256) void knn_mfma(const float* __restrict__ pts,
                                                float4* __restrict__ cand,
                                                unsigned* __restrict__ done) {
  if (blockIdx.x == 0 && threadIdx.x == 0) *done = 0u;
  __shared__ uint4 AF[2][CHUNK_J];      // packed A-frag halves, 32 KB
  const int tid   = threadIdx.x;
  const int chunk = blockIdx.x & (CHUNKS - 1);
  const int ibk   = blockIdx.x >> 4;    // log2(CHUNKS)
  const int j0    = chunk * CHUNK_J;

  // Stage j-side fragments: per j, Kvec as 8 packed words (2 bf16 each).
  for (int t = tid; t < CHUNK_J; t += 256) {
    int j = j0 + t;
    float qx = pts[3 * j], qy = pts[3 * j + 1], qz = pts[3 * j + 2];
    float w  = fmaf(qx, qx, fmaf(qy, qy, qz * qz));
    unsigned Hx, Lx, Hy, Ly, Hz, Lz, Hw, Lw;
    split2(-2.f * qx, Hx, Lx);
    split2(-2.f * qy, Hy, Ly);
    split2(-2.f * qz, Hz, Lz);
    split2(w, Hw, Lw);
    AF[0][t] = make_uint4(Hx | (Hx << 16), Lx | (Lx << 16),
                          Hy | (Hy << 16), Ly | (Ly << 16));
    AF[1][t] = make_uint4(Hz | (Hz << 16), Lz | (Lz << 16),
                          Hw | (Lw << 16), 0u);
  }

  // i-side (B operand) fragment: resident for the whole kernel.
  const int lane = tid & 63, wv = tid >> 6;
  const int h = lane >> 5, il = lane & 31;
  const int i = ibk * IB + wv * 32 + il;
  U128 bf;
  {
    float x = pts[3 * i], y = pts[3 * i + 1], z = pts[3 * i + 2];
    unsigned hx, lx, hy, ly, hz, lz;
    split2(x, hx, lx);
    split2(y, hy, ly);
    split2(z, hz, lz);
    if (h == 0) {
      unsigned a = hx | (lx << 16), b = hy | (ly << 16);
      bf.u = make_uint4(a, a, b, b);
    } else {
      unsigned a = hz | (lz << 16);
      bf.u = make_uint4(a, a, 0x3F803F80u, 0u);   // bf16(1.0) pair
    }
  }
  __syncthreads();

  float b0 = FLT_MAX, b1 = FLT_MAX, b2 = FLT_MAX, b3 = FLT_MAX;
  const f32x16 zacc = {};                          // loop-invariant zero C operand
  const unsigned idb = (unsigned)(chunk * (CHUNK_J / 16));  // global 16-group id base
  const uint4* __restrict__ afp = &AF[h][0];

#pragma unroll 4
  for (int t = 0; t < JTILES; ++t) {
    U128 af; af.u = afp[t * 32 + il];              // conflict-free b128
    f32x16 acc = __builtin_amdgcn_mfma_f32_32x32x16_bf16(af.s, bf.s, zacc, 0, 0, 0);
    // group 2t: rows [0,16) of tile = regs 0..7; group 2t+1: regs 8..15.
    // Left-deep chains -> v_min3 fusion (4 insts per 8-way min).
    float m0 = fminf(fminf(fminf(fminf(fminf(fminf(fminf(
                  acc[0], acc[1]), acc[2]), acc[3]), acc[4]), acc[5]), acc[6]), acc[7]);
    float m1 = fminf(fminf(fminf(fminf(fminf(fminf(fminf(
                  acc[8], acc[9]), acc[10]), acc[11]), acc[12]), acc[13]), acc[14]), acc[15]);
    float k0 = __uint_as_float((__float_as_uint(m0) & 0xFFFFFC00u) | (idb + 2u * t));
    float k1 = __uint_as_float((__float_as_uint(m1) & 0xFFFFFC00u) | (idb + 2u * t + 1u));
    ins4f(k0, b0, b1, b2, b3);
    ins4f(k1, b0, b1, b2, b3);
  }

  // Cross-half merge. Halves hold partial minima over disjoint ROW subsets of
  // the SAME group ids -> dedup: keep smaller of dup pair, re-sort 8 -> top-4.
  float o0 = __shfl_xor(b0, 32), o1 = __shfl_xor(b1, 32),
        o2 = __shfl_xor(b2, 32), o3 = __shfl_xor(b3, 32);
  {
    float B[4] = {b0, b1, b2, b3};
    float O[4] = {o0, o1, o2, o3};
    unsigned ibd[4], iod[4];
#pragma unroll
    for (int k = 0; k < 4; ++k) {
      ibd[k] = __float_as_uint(B[k]) & 0x3FFu;
      iod[k] = __float_as_uint(O[k]) & 0x3FFu;
    }
#pragma unroll
    for (int k = 0; k < 4; ++k) {
#pragma unroll
      for (int m = 0; m < 4; ++m) {
        bool dup = (iod[k] == ibd[m]);
        bool om  = dup && (O[k] >= B[m]);
        bool bm  = dup && (O[k] <  B[m]);
        if (om) O[k] = FLT_MAX;
        if (bm) B[m] = FLT_MAX;
      }
    }
    b0 = b1 = b2 = b3 = FLT_MAX;
#pragma unroll
    for (int k = 0; k < 4; ++k) ins4f(B[k], b0, b1, b2, b3);
#pragma unroll
    for (int k = 0; k < 4; ++k) ins4f(O[k], b0, b1, b2, b3);
  }
  if (h == 0) cand[(size_t)chunk * N_ + i] = make_float4(b0, b1, b2, b3);
}

// grid 256: 64 i's per block; sub-wave w reduces 4 chunks -> sh; ALL waves
// rebuild merged top-4 group list; wave w evaluates group qarr[w] (16 exact-d2
// candidates) -> per-wave top-3 (d2,pred) -> LDS -> wave 0 merges 12 -> top-3.
__global__ __launch_bounds__(256) void merge_kernel(const float* __restrict__ pred,
                                                    const float* __restrict__ targ,
                                                    const float* __restrict__ feat,
                                                    const float* __restrict__ pts,
                                                    const float4* __restrict__ cand,
                                                    float4* __restrict__ part,
                                                    unsigned* __restrict__ done,
                                                    float* __restrict__ out) {
  __shared__ float4 sh[256];
  __shared__ float2 t3[4][3][64];
  __shared__ float ws4[4][4];
  __shared__ int is_last;
  constexpr int CPT = CHUNKS / 4;                  // 4 chunks per sub-wave
  int tid  = threadIdx.x;
  int lane = tid & 63;
  int sub  = tid >> 6;
  int i = blockIdx.x * 64 + lane;

  const float4* f4 = (const float4*)feat;
  float s_sp = 0.f;
#pragma unroll
  for (int s = 0; s < 4; ++s) {
    float4 v = f4[(size_t)s * 65536 + blockIdx.x * 256 + tid];
    s_sp += fabsf(v.x) + fabsf(v.y) + fabsf(v.z) + fabsf(v.w);
  }

  // Phase B: per-sub top-4 over its 4 chunks.
  float b0 = FLT_MAX, b1 = FLT_MAX, b2 = FLT_MAX, b3 = FLT_MAX;
#pragma unroll
  for (int cc = 0; cc < CPT; ++cc) {
    float4 v = cand[(size_t)(sub * CPT + cc) * N_ + i];
    ins4f(v.x, b0, b1, b2, b3);
    ins4f(v.y, b0, b1, b2, b3);
    ins4f(v.z, b0, b1, b2, b3);
    ins4f(v.w, b0, b1, b2, b3);
  }
  sh[tid] = make_float4(b0, b1, b2, b3);
  __syncthreads();

  // Phase C (all waves, identical): merge 4 sub-vectors -> top-4 group ids.
  // Ids are globally distinct across the 4 vectors (chunk-disjoint + knn dedup).
  b0 = b1 = b2 = b3 = FLT_MAX;
#pragma unroll
  for (int w = 0; w < 4; ++w) {
    float4 v = sh[w * 64 + lane];
    ins4f(v.x, b0, b1, b2, b3);
    ins4f(v.y, b0, b1, b2, b3);
    ins4f(v.z, b0, b1, b2, b3);
    ins4f(v.w, b0, b1, b2, b3);
  }
  unsigned qsel;
  {
    float bsel = sub == 0 ? b0 : (sub == 1 ? b1 : (sub == 2 ? b2 : b3));
    qsel = __float_as_uint(bsel) & 0x3FFu;
  }

  // Phase D: wave `sub` evaluates its group's 16 candidates, exact d2.
  float xi = pts[3 * i], yi = pts[3 * i + 1], zi = pts[3 * i + 2];
  float c0 = FLT_MAX, c1 = FLT_MAX, c2 = FLT_MAX;
  float p0 = 0.f, p1 = 0.f, p2 = 0.f;
#pragma unroll 8
  for (int m = 0; m < 16; ++m) {
    int j = (int)(qsel * 16 + m);
    float dx = xi - pts[3 * j], dy = yi - pts[3 * j + 1], dz = zi - pts[3 * j + 2];
    float d2 = fmaf(dx, dx, fmaf(dy, dy, dz * dz));
    float pj = pred[j];
    if (j != i && d2 < c2) {                       // exact top-3, self excluded
      bool cc0 = d2 < c0, cc1 = d2 < c1;
      float n2 = cc1 ? c1 : d2;               float m2 = cc1 ? p1 : pj;
      float n1 = cc0 ? c0 : (cc1 ? d2 : c1);  float m1 = cc0 ? p0 : (cc1 ? pj : p1);
      float n0 = cc0 ? d2 : c0;               float m0 = cc0 ? pj : p0;
      c0 = n0; c1 = n1; c2 = n2; p0 = m0; p1 = m1; p2 = m2;
    }
  }
  t3[sub][0][lane] = make_float2(c0, p0);
  t3[sub][1][lane] = make_float2(c1, p1);
  t3[sub][2][lane] = make_float2(c2, p2);
  __syncthreads();

  // Phase E: wave 0 merges the 4 waves' top-3 -> global top-3 -> scalars.
  float s_occ = 0.f, s_cons = 0.f, s_sm = 0.f;
  if (sub == 0) {
#pragma unroll
    for (int w = 1; w < 4; ++w) {
#pragma unroll
      for (int r = 0; r < 3; ++r) {
        float2 e = t3[w][r][lane];
        float d2 = e.x, pj = e.y;
        if (d2 < c2) {
          bool cc0 = d2 < c0, cc1 = d2 < c1;
          float n2 = cc1 ? c1 : d2;               float m2 = cc1 ? p1 : pj;
          float n1 = cc0 ? c0 : (cc1 ? d2 : c1);  float m1 = cc0 ? p0 : (cc1 ? pj : p1);
          float n0 = cc0 ? d2 : c0;               float m0 = cc0 ? pj : p0;
          c0 = n0; c1 = n1; c2 = n2; p0 = m0; p1 = m1; p2 = m2;
        }
      }
    }
    float pi = pred[i], tg = targ[i];
    float p  = fminf(fmaxf(pi, EPS_), 1.0f - EPS_);
    s_occ  = -(tg * __logf(p) + (1.0f - tg) * __logf(1.0f - p));
    float dd = pi - tg;
    s_cons = dd * dd;
    s_sm   = fabsf(pi - p0) + fabsf(pi - p1) + fabsf(pi - p2);
  }

  for (int off = 32; off > 0; off >>= 1) {
    s_sp   += __shfl_down(s_sp, off);
    s_occ  += __shfl_down(s_occ, off);
    s_cons += __shfl_down(s_cons, off);
    s_sm   += __shfl_down(s_sm, off);
  }
  if ((tid & 63) == 0) {
    int w = tid >> 6;
    ws4[w][0] = s_occ; ws4[w][1] = s_cons; ws4[w][2] = s_sp; ws4[w][3] = s_sm;
  }
  __syncthreads();
  if (tid == 0) {
    part[blockIdx.x] = make_float4(ws4[0][0] + ws4[1][0] + ws4[2][0] + ws4[3][0],
                                   ws4[0][1] + ws4[1][1] + ws4[2][1] + ws4[3][1],
                                   ws4[0][2] + ws4[1][2] + ws4[2][2] + ws4[3][2],
                                   ws4[0][3] + ws4[1][3] + ws4[2][3] + ws4[3][3]);
    __threadfence();
    unsigned prev = atomicAdd(done, 1u);
    is_last = (prev == (unsigned)(gridDim.x - 1));
  }
  __syncthreads();

  if (is_last) {
    __threadfence();
    float4 a = part[tid];
    float o = a.x, cn = a.y, sp = a.z, sm = a.w;
    for (int off = 32; off > 0; off >>= 1) {
      o  += __shfl_down(o, off);
      cn += __shfl_down(cn, off);
      sp += __shfl_down(sp, off);
      sm += __shfl_down(sm, off);
    }
    if ((tid & 63) == 0) {
      int w = tid >> 6;
      ws4[w][0] = o; ws4[w][1] = cn; ws4[w][2] = sp; ws4[w][3] = sm;
    }
    __syncthreads();
    if (tid == 0) {
      float occ  = ws4[0][0] + ws4[1][0] + ws4[2][0] + ws4[3][0];
      float cons = ws4[0][1] + ws4[1][1] + ws4[2][1] + ws4[3][1];
      float spar = ws4[0][2] + ws4[1][2] + ws4[2][2] + ws4[3][2];
      float smoo = ws4[0][3] + ws4[1][3] + ws4[2][3] + ws4[3][3];
      out[0] = OCC_W * (occ / (float)N_)
             + CONS_W * (cons / (float)N_)
             + SPARSE_W * (spar / (float)(N_ * F_))
             + SMOOTH_W * (smoo / (float)(N_ * 3));
    }
  }
}

extern "C" void kernel_launch(void* const* d_in, const int* in_sizes, int n_in,
                              void* d_out, int out_size, void* d_ws, size_t ws_size,
                              hipStream_t stream) {
  const float* pred = (const float*)d_in[0];
  const float* targ = (const float*)d_in[1];
  const float* feat = (const float*)d_in[2];
  const float* pts  = (const float*)d_in[3];
  float* out = (float*)d_out;

  char*     ws   = (char*)d_ws;
  float4*   part = (float4*)ws;
  unsigned* done = (unsigned*)(ws + 4096);
  float4*   cand = (float4*)(ws + 8192);

  knn_mfma<<<IBLOCKS * CHUNKS, 256, 0, stream>>>(pts, cand, done);
  merge_kernel<<<256, 256, 0, stream>>>(pred, targ, feat, pts, cand, part, done, out);
}